// Round 6
// baseline (1268.885 us; speedup 1.0000x reference)
//
#include <hip/hip_runtime.h>
#include <hip/hip_fp16.h>

// CRF mean-field, NHWC. Per iter: out = x + sw * blurW(blurH(softmax_C(xc)))
//
// R5 (resubmit; previous round was an infra failure, kernel never ran):
// R4's planar fp16 layout + COALESCED global I/O (R4 was VMEM-transaction
// bound: 21 scalar loads/pixel at 84B stride = ~55 cache lines per wave-load;
// VALU 32%, HBM 42%, occupancy 60% all unsaturated while TA pipe saturated).
//
//  P1 stage:  wave loads 64 CONSECUTIVE dwords per halo row (4-5 lines per
//             wave-load), cvt fp16, b16 scatter into planar LDS (<=3-way).
//             Per-thread (px,c) fixed; row loop adds constant strides.
//  prefetch:  unary float4 chunks -> registers (issued before first barrier,
//             consumed in P5; HBM latency hides under P2-P4).
//  P2 softmax: 11 aligned b32 planar reads, f32 max/exp/sum (proven accuracy),
//             11 b32 writes. In place.
//  P3 vblur:  packed v_pk_fma_f16 columns, in place (rows 0..15).   [R4]
//  P4 hblur:  b128 rows, pk fma, sw folded into taps, in place.     [R4]
//  P5 epilog: out = unary(reg) + s via float4 stores; s gathered with 4 b16
//             planar reads per chunk (incremental address walk).
//
// In-place safety: P2 pixel-private, P3 column-private, P4 row-private (all
// taps in registers before any write); 4 barriers total.
// fp16 API surface: __half2, __float2half_rn, __half2float,
// __floats2half2_rn, __half22float2 (all compile-proven on ROCm 7.2) +
// inline-asm v_pk_{add,mul,fma}_f16 (proven R4).

#define BB    16
#define Himg  384
#define Wimg  384
#define CC    21
#define NP    11                   // channel pairs (last = c20 + zero pad)
#define TH    16
#define TW    16
#define RR    4
#define PH    (TH + 2*RR)          // 24
#define PW    (TW + 2*RR)          // 24
#define NPIX  (PH * PW)            // 576
#define ROWF_F (PW * CC)           // 504 dwords per halo row
#define PLANE_B 2384               // plane stride bytes (2304 + 80 pad; /4 %32 = 20)
#define ROW_B   (PW * 4)           // 96 B per plane row (24 slots)
#define NTASK (PW * NP)            // 264 (col, plane) tasks
#define NTOT  (BB * Himg * Wimg * CC)  // 49545216
#define RCHUNKS (TW * CC / 4)      // 84 float4 per tile row
#define NCHUNK5 (TH * RCHUNKS)     // 1344 output chunks

static __device__ __forceinline__ unsigned int pk_add(unsigned int a, unsigned int b) {
    unsigned int d; asm("v_pk_add_f16 %0, %1, %2" : "=v"(d) : "v"(a), "v"(b)); return d;
}
static __device__ __forceinline__ unsigned int pk_mul(unsigned int a, unsigned int b) {
    unsigned int d; asm("v_pk_mul_f16 %0, %1, %2" : "=v"(d) : "v"(a), "v"(b)); return d;
}
static __device__ __forceinline__ unsigned int pk_fma(unsigned int a, unsigned int b, unsigned int c) {
    unsigned int d; asm("v_pk_fma_f16 %0, %1, %2, %3" : "=v"(d) : "v"(a), "v"(b), "v"(c)); return d;
}

__global__ __launch_bounds__(256, 6)
void crf_iter_kernel(const float* __restrict__ xin,
                     const float* __restrict__ unary,
                     float* __restrict__ out,
                     const float* __restrict__ spacings,
                     const float* __restrict__ inv_theta,
                     const float* __restrict__ sw_ptr)
{
    __shared__ __align__(16) unsigned char smem[NP * PLANE_B];  // 26224 B

    const int tid = threadIdx.x;
    const int b   = blockIdx.z;
    const int h0  = blockIdx.y * TH;
    const int w0  = blockIdx.x * TW;

    const float sp_h = spacings[b * 2 + 0];
    const float sp_w = spacings[b * 2 + 1];
    const float ith  = inv_theta[0];
    const float itw  = inv_theta[1];
    const float sw   = sw_ptr[0];
    // symmetric taps: k[i] == k[8-i]; center (i==4) excluded. Keep 4 each.
    unsigned int khp[4], kwp[4];
#pragma unroll
    for (int i = 0; i < 4; ++i) {
        float dh = sp_h * (float)(i - 4) * ith;
        float dw = sp_w * (float)(i - 4) * itw;
        float kh = __expf(-0.5f * dh * dh);
        float kw = sw * __expf(-0.5f * dw * dw);   // fold sw into horizontal
        __half2 a = __floats2half2_rn(kh, kh);
        __half2 c = __floats2half2_rn(kw, kw);
        khp[i] = *(unsigned int*)&a;
        kwp[i] = *(unsigned int*)&c;
    }

    // ---- Phase 1: coalesced halo load -> planar fp16 scatter ----
    // Lanes own consecutive row-dwords qq: global loads are 64 consecutive
    // dwords per wave. Row-OOB rows skipped (uniform branch); col-OOB lanes
    // load clamped garbage that P2 overwrites with zeros.
    for (int qq = tid; qq < ROWF_F; qq += 256) {     // <=2 iterations
        const int px = qq / CC;
        const int c  = qq - px * CC;
        unsigned char* dst = smem + (c >> 1) * PLANE_B + px * 4 + ((c & 1) << 1);
        int basef = ((b * Himg + (h0 - RR)) * Wimg + (w0 - RR)) * CC + qq;
#pragma unroll
        for (int r = 0; r < PH; ++r) {
            const int hh = h0 - RR + r;              // block-uniform branch
            if (hh >= 0 && hh < Himg) {
                int a = basef < 0 ? 0 : (basef > NTOT - 1 ? NTOT - 1 : basef);
                *(__half*)(dst + r * ROW_B) = __float2half_rn(xin[a]);
            }
            basef += Wimg * CC;
        }
    }

    // ---- unary prefetch for P5 (issue early, consume after P4) ----
    const int gbase = ((b * Himg + h0) * Wimg + w0) * CC;
    float4 uf[6];
#pragma unroll
    for (int k = 0; k < 6; ++k) {
        const int j = tid + k * 256;
        if (j < NCHUNK5) {
            const int hrow = j / RCHUNKS;
            const int qq   = j - hrow * RCHUNKS;
            uf[k] = *(const float4*)(unary + gbase + hrow * (Wimg * CC) + qq * 4);
        }
    }
    __syncthreads();

    // ---- Phase 2: f32 softmax over C from planar LDS, in place ----
    for (int p = tid; p < NPIX; p += 256) {
        const int r  = p / PW;
        const int px = p - r * PW;
        const int hh = h0 - RR + r;
        const int gw = w0 - RR + px;
        unsigned char* lbase = smem + p * 4;   // p*4 == r*ROW_B + px*4
        if (hh >= 0 && hh < Himg && gw >= 0 && gw < Wimg) {
            float v[22];
#pragma unroll
            for (int cp = 0; cp < NP; ++cp) {
                float2 f = __half22float2(*(const __half2*)(lbase + cp * PLANE_B));
                v[2*cp] = f.x; v[2*cp+1] = f.y;   // v[21] = pad garbage, unused
            }
            float m = v[0];
#pragma unroll
            for (int c = 1; c < CC; ++c) m = fmaxf(m, v[c]);
            float s = 0.f;
#pragma unroll
            for (int c = 0; c < CC; ++c) { v[c] = __expf(v[c] - m); s += v[c]; }
            const float inv = 1.0f / s;
#pragma unroll
            for (int cp = 0; cp < 10; ++cp)
                *(__half2*)(lbase + cp * PLANE_B) =
                    __floats2half2_rn(v[2*cp] * inv, v[2*cp+1] * inv);
            *(__half2*)(lbase + 10 * PLANE_B) = __floats2half2_rn(v[20] * inv, 0.f);
        } else {
            const __half2 z = __floats2half2_rn(0.f, 0.f);
#pragma unroll
            for (int cp = 0; cp < NP; ++cp)
                *(__half2*)(lbase + cp * PLANE_B) = z;
        }
    }
    __syncthreads();

    // ---- Phase 3: vertical blur, packed fp16, in place (rows 0..15) ----
    for (int t = tid; t < NTASK; t += 256) {
        const int cp  = t / PW;
        const int col = t - cp * PW;
        unsigned char* base = smem + cp * PLANE_B + col * 4;
        unsigned int v[PH];
#pragma unroll
        for (int r = 0; r < PH; ++r) v[r] = *(const unsigned int*)(base + r * ROW_B);
#pragma unroll
        for (int tt = 0; tt < TH; ++tt) {
            unsigned int s0 = pk_add(v[tt],     v[tt + 8]);
            unsigned int s1 = pk_add(v[tt + 1], v[tt + 7]);
            unsigned int s2 = pk_add(v[tt + 2], v[tt + 6]);
            unsigned int s3 = pk_add(v[tt + 3], v[tt + 5]);
            unsigned int acc = pk_mul(khp[0], s0);
            acc = pk_fma(khp[1], s1, acc);
            acc = pk_fma(khp[2], s2, acc);
            acc = pk_fma(khp[3], s3, acc);
            *(unsigned int*)(base + tt * ROW_B) = acc;
        }
    }
    __syncthreads();

    // ---- Phase 4: horizontal blur * sw, b128 rows, in place (cols 0..15) ----
    if (tid < TH * NP) {                   // 176 tasks
        const int h  = tid / NP;
        const int cp = tid - h * NP;
        unsigned char* base = smem + cp * PLANE_B + h * ROW_B;
        unsigned int v[PW];
#pragma unroll
        for (int k = 0; k < 6; ++k) {
            const uint4 q = *(const uint4*)(base + k * 16);
            v[4*k+0] = q.x; v[4*k+1] = q.y; v[4*k+2] = q.z; v[4*k+3] = q.w;
        }
        unsigned int o[TW];
#pragma unroll
        for (int wt = 0; wt < TW; ++wt) {
            unsigned int s0 = pk_add(v[wt],     v[wt + 8]);
            unsigned int s1 = pk_add(v[wt + 1], v[wt + 7]);
            unsigned int s2 = pk_add(v[wt + 2], v[wt + 6]);
            unsigned int s3 = pk_add(v[wt + 3], v[wt + 5]);
            unsigned int acc = pk_mul(kwp[0], s0);
            acc = pk_fma(kwp[1], s1, acc);
            acc = pk_fma(kwp[2], s2, acc);
            acc = pk_fma(kwp[3], s3, acc);
            o[wt] = acc;
        }
#pragma unroll
        for (int k = 0; k < 4; ++k) {
            uint4 wq;
            wq.x = o[4*k+0]; wq.y = o[4*k+1]; wq.z = o[4*k+2]; wq.w = o[4*k+3];
            *(uint4*)(base + k * 16) = wq;
        }
    }
    __syncthreads();

    // ---- Phase 5: out = unary(reg) + s, float4 stores, planar b16 walk ----
    // s lives at planar rows 0..15 (h), cols 0..15 (wt). Walk per chunk:
    //   (px, even c<20) -> +2 ; (px, odd c) -> +(PLANE_B-2) ;
    //   (px, 20) -> (px+1, 0): +(4 - 10*PLANE_B).
#pragma unroll
    for (int k = 0; k < 6; ++k) {
        const int j = tid + k * 256;
        if (j < NCHUNK5) {
            const int hrow = j / RCHUNKS;
            const int qq   = j - hrow * RCHUNKS;
            const int f    = qq * 4;
            int px = f / 21;
            int c  = f - px * 21;
            int addr = (c >> 1) * PLANE_B + hrow * ROW_B + px * 4 + (c & 1) * 2;
            float sv[4];
#pragma unroll
            for (int i = 0; i < 4; ++i) {
                sv[i] = __half2float(*(const __half*)(smem + addr));
                const int wrap = (c == 20);
                const int odd  = c & 1;
                addr += wrap ? (4 - 10 * PLANE_B) : (odd ? (PLANE_B - 2) : 2);
                c = wrap ? 0 : c + 1;
            }
            const float4 u = uf[k];
            float4 o;
            o.x = u.x + sv[0]; o.y = u.y + sv[1];
            o.z = u.z + sv[2]; o.w = u.w + sv[3];
            *(float4*)(out + gbase + hrow * (Wimg * CC) + qq * 4) = o;
        }
    }
}

extern "C" void kernel_launch(void* const* d_in, const int* in_sizes, int n_in,
                              void* d_out, int out_size, void* d_ws, size_t ws_size,
                              hipStream_t stream) {
    const float* x         = (const float*)d_in[0];
    const float* spacings  = (const float*)d_in[1];
    const float* sw        = (const float*)d_in[2];
    const float* inv_theta = (const float*)d_in[3];
    float* out = (float*)d_out;
    float* ws  = (float*)d_ws;

    dim3 grid(Wimg / TW, Himg / TH, BB);   // 24 x 24 x 16 = 9216 blocks
    dim3 block(256);

    crf_iter_kernel<<<grid, block, 0, stream>>>(x,   x, out, spacings, inv_theta, sw);
    crf_iter_kernel<<<grid, block, 0, stream>>>(out, x, ws,  spacings, inv_theta, sw);
    crf_iter_kernel<<<grid, block, 0, stream>>>(ws,  x, out, spacings, inv_theta, sw);
    crf_iter_kernel<<<grid, block, 0, stream>>>(out, x, ws,  spacings, inv_theta, sw);
    crf_iter_kernel<<<grid, block, 0, stream>>>(ws,  x, out, spacings, inv_theta, sw);
}

// Round 7
// 820.278 us; speedup vs baseline: 1.5469x; 1.5469x over previous
//
#include <hip/hip_runtime.h>
#include <hip/hip_fp16.h>

// CRF mean-field, NHWC. Per iter: out = x + sw * blurW(blurH(softmax_C(xc)))
//
// R7 = R4 (proven 148 us/dispatch) + two isolated changes:
//  (a) P5 epilogue: float4 unary read + float4 out store (coalesced 16B
//      chunks; was 21 scalar ld + 21 scalar st per pixel at 84B stride),
//      s gathered from planar LDS via the proven incremental b16 walk.
//  (b) XCD-aware bijective block swizzle (9216 % 8 == 0): consecutive HW
//      block IDs round-robin across XCDs; remap so each XCD owns 1152
//      consecutive tiles (2 images) -> halo refetch of adjacent tiles
//      becomes same-L2 hit instead of HBM/L3.
// Everything else verbatim R4: fused global-scalar softmax (P2), packed
// v_pk_fma_f16 blurs (P3/P4) on planar channel-pair fp16 LDS, in place.
//
// In-place safety: P2 pixel-private, P3 column-private, P4 row-private
// (all taps in registers before any write); 3 barriers total.

#define BB    16
#define Himg  384
#define Wimg  384
#define CC    21
#define NP    11                   // channel pairs (last = c20 + zero pad)
#define TH    16
#define TW    16
#define RR    4
#define PH    (TH + 2*RR)          // 24
#define PW    (TW + 2*RR)          // 24
#define NPIX  (PH * PW)            // 576
#define PLANE_B 2384               // plane stride bytes (2304 + 80 pad; /4 %32 = 20)
#define ROW_B   (PW * 4)           // 96 B per plane row (24 slots)
#define NTASK (PW * NP)            // 264 (col, plane) tasks
#define RCHUNKS (TW * CC / 4)      // 84 float4 per tile row
#define NCHUNK5 (TH * RCHUNKS)     // 1344 output chunks
#define NTILES  (24 * 24 * BB)     // 9216

static __device__ __forceinline__ unsigned int pk_add(unsigned int a, unsigned int b) {
    unsigned int d; asm("v_pk_add_f16 %0, %1, %2" : "=v"(d) : "v"(a), "v"(b)); return d;
}
static __device__ __forceinline__ unsigned int pk_mul(unsigned int a, unsigned int b) {
    unsigned int d; asm("v_pk_mul_f16 %0, %1, %2" : "=v"(d) : "v"(a), "v"(b)); return d;
}
static __device__ __forceinline__ unsigned int pk_fma(unsigned int a, unsigned int b, unsigned int c) {
    unsigned int d; asm("v_pk_fma_f16 %0, %1, %2, %3" : "=v"(d) : "v"(a), "v"(b), "v"(c)); return d;
}

__global__ __launch_bounds__(256, 6)
void crf_iter_kernel(const float* __restrict__ xin,
                     const float* __restrict__ unary,
                     float* __restrict__ out,
                     const float* __restrict__ spacings,
                     const float* __restrict__ inv_theta,
                     const float* __restrict__ sw_ptr)
{
    __shared__ __align__(16) unsigned char smem[NP * PLANE_B];  // 26224 B

    const int tid = threadIdx.x;

    // ---- XCD-aware bijective swizzle: each XCD gets 1152 contiguous tiles ----
    const int lin = blockIdx.x + 24 * (blockIdx.y + 24 * blockIdx.z);
    const int swz = (lin & 7) * (NTILES / 8) + (lin >> 3);
    const int b   = swz / 576;
    const int rem = swz - b * 576;
    const int ty  = rem / 24;
    const int h0  = ty * TH;
    const int w0  = (rem - ty * 24) * TW;

    const float sp_h = spacings[b * 2 + 0];
    const float sp_w = spacings[b * 2 + 1];
    const float ith  = inv_theta[0];
    const float itw  = inv_theta[1];
    const float sw   = sw_ptr[0];
    // symmetric taps: k[i] == k[8-i]; center (i==4) excluded. Keep 4 each.
    unsigned int khp[4], kwp[4];
#pragma unroll
    for (int i = 0; i < 4; ++i) {
        float dh = sp_h * (float)(i - 4) * ith;
        float dw = sp_w * (float)(i - 4) * itw;
        float kh = __expf(-0.5f * dh * dh);
        float kw = sw * __expf(-0.5f * dw * dw);   // fold sw into horizontal
        __half2 a = __floats2half2_rn(kh, kh);
        __half2 c = __floats2half2_rn(kw, kw);
        khp[i] = *(unsigned int*)&a;
        kwp[i] = *(unsigned int*)&c;
    }

    // ---- Phase 2 (fused stage+softmax): global -> regs -> planar LDS ----
    for (int p = tid; p < NPIX; p += 256) {
        const int r  = p / PW;
        const int px = p - r * PW;
        const int hh = h0 - RR + r;
        const int gw = w0 - RR + px;
        // planar slot: addr/4 = p + plane*596 -> consecutive lanes,
        // consecutive banks: conflict-free.
        unsigned char* lbase = smem + p * 4;
        if (hh >= 0 && hh < Himg && gw >= 0 && gw < Wimg) {
            const float* gp = xin + ((b * Himg + hh) * Wimg + gw) * CC;
            float v[CC];
#pragma unroll
            for (int c = 0; c < CC; ++c) v[c] = gp[c];   // 21 dword, imm offs
            float m = v[0];
#pragma unroll
            for (int c = 1; c < CC; ++c) m = fmaxf(m, v[c]);
            float s = 0.f;
#pragma unroll
            for (int c = 0; c < CC; ++c) { v[c] = __expf(v[c] - m); s += v[c]; }
            const float inv = 1.0f / s;
#pragma unroll
            for (int cp = 0; cp < 10; ++cp) {
                __half2 hx = __floats2half2_rn(v[2*cp] * inv, v[2*cp+1] * inv);
                *(__half2*)(lbase + cp * PLANE_B) = hx;
            }
            __half2 hl = __floats2half2_rn(v[20] * inv, 0.f);  // pad slot = 0
            *(__half2*)(lbase + 10 * PLANE_B) = hl;
        } else {
            const __half2 z = __floats2half2_rn(0.f, 0.f);
#pragma unroll
            for (int cp = 0; cp < NP; ++cp)
                *(__half2*)(lbase + cp * PLANE_B) = z;
        }
    }
    __syncthreads();

    // ---- Phase 3: vertical blur, packed fp16, in place (rows 0..15) ----
    for (int t = tid; t < NTASK; t += 256) {
        const int cp  = t / PW;
        const int col = t - cp * PW;
        unsigned char* base = smem + cp * PLANE_B + col * 4;
        unsigned int v[PH];
#pragma unroll
        for (int r = 0; r < PH; ++r) v[r] = *(const unsigned int*)(base + r * ROW_B);
#pragma unroll
        for (int tt = 0; tt < TH; ++tt) {
            unsigned int s0 = pk_add(v[tt],     v[tt + 8]);
            unsigned int s1 = pk_add(v[tt + 1], v[tt + 7]);
            unsigned int s2 = pk_add(v[tt + 2], v[tt + 6]);
            unsigned int s3 = pk_add(v[tt + 3], v[tt + 5]);
            unsigned int acc = pk_mul(khp[0], s0);
            acc = pk_fma(khp[1], s1, acc);
            acc = pk_fma(khp[2], s2, acc);
            acc = pk_fma(khp[3], s3, acc);
            *(unsigned int*)(base + tt * ROW_B) = acc;
        }
    }
    __syncthreads();

    // ---- Phase 4: horizontal blur * sw, b128 rows, in place (cols 0..15) ----
    if (tid < TH * NP) {                   // 176 tasks
        const int h  = tid / NP;
        const int cp = tid - h * NP;
        unsigned char* base = smem + cp * PLANE_B + h * ROW_B;
        unsigned int v[PW];
#pragma unroll
        for (int k = 0; k < 6; ++k) {
            const uint4 q = *(const uint4*)(base + k * 16);
            v[4*k+0] = q.x; v[4*k+1] = q.y; v[4*k+2] = q.z; v[4*k+3] = q.w;
        }
        unsigned int o[TW];
#pragma unroll
        for (int wt = 0; wt < TW; ++wt) {
            unsigned int s0 = pk_add(v[wt],     v[wt + 8]);
            unsigned int s1 = pk_add(v[wt + 1], v[wt + 7]);
            unsigned int s2 = pk_add(v[wt + 2], v[wt + 6]);
            unsigned int s3 = pk_add(v[wt + 3], v[wt + 5]);
            unsigned int acc = pk_mul(kwp[0], s0);
            acc = pk_fma(kwp[1], s1, acc);
            acc = pk_fma(kwp[2], s2, acc);
            acc = pk_fma(kwp[3], s3, acc);
            o[wt] = acc;
        }
#pragma unroll
        for (int k = 0; k < 4; ++k) {
            uint4 wq;
            wq.x = o[4*k+0]; wq.y = o[4*k+1]; wq.z = o[4*k+2]; wq.w = o[4*k+3];
            *(uint4*)(base + k * 16) = wq;
        }
    }
    __syncthreads();

    // ---- Phase 5: out = unary + s, float4 I/O, planar b16 walk ----
    // s lives at planar rows 0..15 (h), cols 0..15 (wt). Walk per chunk:
    //   (px, even c<20) -> +2 ; (px, odd c) -> +(PLANE_B-2) ;
    //   (px, 20) -> (px+1, 0): +(4 - 10*PLANE_B).
    {
        const int gbase = ((b * Himg + h0) * Wimg + w0) * CC;
        for (int j = tid; j < NCHUNK5; j += 256) {
            const int hrow = j / RCHUNKS;
            const int qq   = j - hrow * RCHUNKS;
            const int f    = qq * 4;
            int px = f / 21;
            int c  = f - px * 21;
            int addr = (c >> 1) * PLANE_B + hrow * ROW_B + px * 4 + (c & 1) * 2;
            float sv[4];
#pragma unroll
            for (int i = 0; i < 4; ++i) {
                sv[i] = __half2float(*(const __half*)(smem + addr));
                const int wrap = (c == 20);
                const int odd  = c & 1;
                addr += wrap ? (4 - 10 * PLANE_B) : (odd ? (PLANE_B - 2) : 2);
                c = wrap ? 0 : c + 1;
            }
            const int g = gbase + hrow * (Wimg * CC) + f;
            const float4 u = *(const float4*)(unary + g);
            float4 o;
            o.x = u.x + sv[0]; o.y = u.y + sv[1];
            o.z = u.z + sv[2]; o.w = u.w + sv[3];
            *(float4*)(out + g) = o;
        }
    }
}

extern "C" void kernel_launch(void* const* d_in, const int* in_sizes, int n_in,
                              void* d_out, int out_size, void* d_ws, size_t ws_size,
                              hipStream_t stream) {
    const float* x         = (const float*)d_in[0];
    const float* spacings  = (const float*)d_in[1];
    const float* sw        = (const float*)d_in[2];
    const float* inv_theta = (const float*)d_in[3];
    float* out = (float*)d_out;
    float* ws  = (float*)d_ws;

    dim3 grid(Wimg / TW, Himg / TH, BB);   // 24 x 24 x 16 = 9216 blocks
    dim3 block(256);

    crf_iter_kernel<<<grid, block, 0, stream>>>(x,   x, out, spacings, inv_theta, sw);
    crf_iter_kernel<<<grid, block, 0, stream>>>(out, x, ws,  spacings, inv_theta, sw);
    crf_iter_kernel<<<grid, block, 0, stream>>>(ws,  x, out, spacings, inv_theta, sw);
    crf_iter_kernel<<<grid, block, 0, stream>>>(out, x, ws,  spacings, inv_theta, sw);
    crf_iter_kernel<<<grid, block, 0, stream>>>(ws,  x, out, spacings, inv_theta, sw);
}